// Round 13
// baseline (61.577 us; speedup 1.0000x reference)
//
#include <hip/hip_runtime.h>
#include <hip/hip_bf16.h>

#define NB 8
#define SEQ 2048
#define HD 1024
#define DK 64

// exp2-domain constants: Q pre-scaled by 0.125/ln2, fixed softmax base 8/ln2
#define QSCALE 0.1803368801111244f
#define FIXMAX2 11.541560327111708f

typedef __attribute__((ext_vector_type(4))) float f32x4;
typedef __attribute__((ext_vector_type(8))) short bf16x8;
typedef __attribute__((ext_vector_type(4))) unsigned short u16x4;

// raw barrier: LDS-only fence (lgkmcnt), NO vmcnt drain -> global loads stay in flight
#define LDS_BARRIER() asm volatile("s_waitcnt lgkmcnt(0)\n\ts_barrier" ::: "memory")

__device__ __forceinline__ short f2bf(float f) {
    union { float f; unsigned u; } v; v.f = f;
    unsigned r = v.u + 0x7fffu + ((v.u >> 16) & 1u);
    return (short)(r >> 16);
}
__device__ __forceinline__ bf16x8 pack8(f32x4 v0, f32x4 v1) {
    union { bf16x8 v; __hip_bfloat162 h[4]; } u;
    u.h[0] = __float22bfloat162_rn(make_float2(v0[0], v0[1]));
    u.h[1] = __float22bfloat162_rn(make_float2(v0[2], v0[3]));
    u.h[2] = __float22bfloat162_rn(make_float2(v1[0], v1[1]));
    u.h[3] = __float22bfloat162_rn(make_float2(v1[2], v1[3]));
    return u.v;
}

// ---------------- prep: W pack (blocks 0..767) + lengths (768..775) ----------------
// Wp2[(((kbg*4+cg)*2+kh)*3+fr)*512 + lane*8 + j] = W_m[k][colm]
__global__ void prep_kernel(const unsigned* __restrict__ mask,
                            const float* __restrict__ Wq, const float* __restrict__ Wk,
                            const float* __restrict__ Wv,
                            int* __restrict__ lengths, short* __restrict__ Wp) {
    if (blockIdx.x < 768) {
        int idx = blockIdx.x * 256 + threadIdx.x;     // 0..196607
        int j = idx & 7, lane = (idx >> 3) & 63;
        int slot = idx >> 9;                          // 0..383
        int fr = slot % 3, q2 = slot / 3;
        int kh = q2 & 1, cg = (q2 >> 1) & 3, kbg = q2 >> 3;
        int g = lane >> 4, c = lane & 15;
        int n = cg * 3 + fr;
        int m = n >> 2, colm = (n & 3) * 16 + c;
        int k = kbg * 64 + kh * 32 + g * 8 + j;
        const float* W = (m == 0) ? Wq : (m == 1) ? Wk : Wv;
        Wp[idx] = f2bf(W[(size_t)k * DK + colm]);
        return;
    }
    __shared__ int sdet;
    __shared__ int scnt;
    int b = blockIdx.x - 768, t = threadIdx.x;
    if (t == 0) { sdet = 0; scnt = 0; }
    __syncthreads();
    int det = 0;
    for (int i = t; i < 4096; i += 256) {
        unsigned w = mask[i];
        if (w > 1u && w != 0x3F800000u) det = 1;
    }
    if (det) atomicOr(&sdet, 1);
    __syncthreads();
    int cnt = 0;
    if (sdet) {
        const unsigned char* m8 = (const unsigned char*)mask;
        for (int s = t; s < SEQ; s += 256) cnt += (m8[b * SEQ + s] == 0) ? 1 : 0;
    } else {
        for (int s = t; s < SEQ; s += 256) cnt += (mask[b * SEQ + s] == 0u) ? 1 : 0;
    }
    atomicAdd(&scnt, cnt);
    __syncthreads();
    if (t == 0) lengths[b] = scnt;
}

// ---------------- QKV v11: bf16-in-LDS dbuf GEMM, counted-vmcnt pipeline -----------
__global__ __launch_bounds__(256) void qkv_kernel(
    const float* __restrict__ x,
    const float* __restrict__ bq, const float* __restrict__ bk, const float* __restrict__ bv,
    const short* __restrict__ Wp,
    short* __restrict__ Q, short* __restrict__ K, short* __restrict__ Vt) {
    __shared__ short xs[2][32][64];    // 8 KiB bf16, granule-swizzled
    int t = threadIdx.x;
    int cg = t >> 6, lane = t & 63;
    int g = lane >> 4, c = lane & 15;
    int r0 = blockIdx.x * 32;
    int bb = r0 >> 11, sbase = r0 & (SEQ - 1);

    int srow = t >> 3, ch = t & 7;
    const float* xsrc = x + (size_t)(r0 + srow) * HD + ch * 8;
    short* wbase = &xs[0][0][0];
    int wo = srow * 64 + ((ch ^ (srow & 7)) << 3);    // shorts

    const short* wpw = Wp + (size_t)cg * 3072 + (size_t)lane * 8;

    f32x4 z = {0.f, 0.f, 0.f, 0.f};
    f32x4 acc[2][3];
    #pragma unroll
    for (int rf = 0; rf < 2; rf++)
        #pragma unroll
        for (int fr = 0; fr < 3; fr++) acc[rf][fr] = z;

    // prologue: stage step 0 (convert at write), preload B step 0, issue x step 1
    {
        f32x4 x0 = *(const f32x4*)xsrc;
        f32x4 x1 = *(const f32x4*)(xsrc + 4);
        *(bf16x8*)(wbase + wo) = pack8(x0, x1);
    }
    bf16x8 Bc[2][3];
    #pragma unroll
    for (int kh = 0; kh < 2; kh++)
        #pragma unroll
        for (int fr = 0; fr < 3; fr++)
            Bc[kh][fr] = *(const bf16x8*)(wpw + kh * 1536 + fr * 512);
    f32x4 nxA0 = *(const f32x4*)(xsrc + 64);
    f32x4 nxA1 = *(const f32x4*)(xsrc + 68);
    LDS_BARRIER();

    const short* rbase0 = &xs[0][0][0] + c * 64;   // + cur*2048 + rf*1024 + chunk*8
    #pragma unroll
    for (int kbg = 0; kbg < 16; kbg++) {
        int cur = kbg & 1;
        // issue x loads for kbg+2 (2-deep) and B loads for kbg+1 (1-deep) FIRST
        f32x4 nxB0, nxB1;
        bf16x8 Bn[2][3];
        if (kbg < 14) {
            const float* p = xsrc + (kbg + 2) * 64;
            nxB0 = *(const f32x4*)p;
            nxB1 = *(const f32x4*)(p + 4);
        }
        if (kbg < 15) {
            #pragma unroll
            for (int kh = 0; kh < 2; kh++)
                #pragma unroll
                for (int fr = 0; fr < 3; fr++)
                    Bn[kh][fr] = *(const bf16x8*)(wpw + (kbg + 1) * 12288 + kh * 1536 + fr * 512);
        }
        // A frags: direct bf16 ds_read_b128 (no conversion)
        bf16x8 Af[2][2];
        #pragma unroll
        for (int rf = 0; rf < 2; rf++)
            #pragma unroll
            for (int kh = 0; kh < 2; kh++)
                Af[rf][kh] = *(const bf16x8*)(rbase0 + cur * 2048 + rf * 1024
                                              + (((kh * 4 + g) ^ (c & 7)) << 3));
        #pragma unroll
        for (int kh = 0; kh < 2; kh++)
            #pragma unroll
            for (int fr = 0; fr < 3; fr++)
                #pragma unroll
                for (int rf = 0; rf < 2; rf++)
                    acc[rf][fr] = __builtin_amdgcn_mfma_f32_16x16x32_bf16(Af[rf][kh], Bc[kh][fr], acc[rf][fr], 0, 0, 0);
        if (kbg < 15) {
            // counted vmcnt wait lands here (nxA issued 2 steps ago)
            *(bf16x8*)(wbase + (cur ^ 1) * 2048 + wo) = pack8(nxA0, nxA1);
            #pragma unroll
            for (int kh = 0; kh < 2; kh++)
                #pragma unroll
                for (int fr = 0; fr < 3; fr++) Bc[kh][fr] = Bn[kh][fr];
        }
        if (kbg < 14) { nxA0 = nxB0; nxA1 = nxB1; }
        LDS_BARRIER();
    }

    // epilogue
    #pragma unroll
    for (int rf = 0; rf < 2; rf++)
        #pragma unroll
        for (int fr = 0; fr < 3; fr++) {
            int n = cg * 3 + fr;
            int m = n >> 2, colm = (n & 3) * 16 + c;
            const float* bias = (m == 0) ? bq : (m == 1) ? bk : bv;
            float bv_ = bias[colm];
            if (m == 2) {
                u16x4 pk;
                #pragma unroll
                for (int j = 0; j < 4; j++) pk[j] = (unsigned short)f2bf(acc[rf][fr][j] + bv_);
                int srw = sbase + rf * 16 + 4 * g;
                *(u16x4*)(Vt + (size_t)bb * DK * SEQ + (size_t)colm * SEQ + srw) = pk;
            } else {
                #pragma unroll
                for (int j = 0; j < 4; j++) {
                    int row = r0 + rf * 16 + 4 * g + j;
                    float s = acc[rf][fr][j] + bv_;
                    if (m == 0) Q[(size_t)row * DK + colm] = f2bf(s * QSCALE);
                    else        K[(size_t)row * DK + colm] = f2bf(s);
                }
            }
        }
}

// ---------------- flash attention v13: block-cooperative LDS-staged tiles ----------
// Block = 32-row q-tile, 8 waves = 2 row-halves x 4 key-quarters. Each 64-key tile
// staged ONCE into LDS (K+V dbuf, 2-deep reg prefetch, counted-vmcnt barriers) and
// computed by all waves. Key-quarter pairs share a P buffer so PV runs the verified
// 16x16x32 shape over 32 keys. VGPR ~110 -> 4 waves/SIMD; LDS 54 KB -> 2 blocks/CU.
__global__ __launch_bounds__(512) void attn_kernel(
    const short* __restrict__ Q, const short* __restrict__ K_, const short* __restrict__ Vt,
    const int* __restrict__ lengths, float* __restrict__ out) {
    __shared__ __align__(16) short ksd[2][64][64];   // K tiles [key][dk], 16 KiB
    __shared__ __align__(16) short vsd[2][64][64];   // V^T tiles [d][key], 16 KiB
    __shared__ __align__(16) short pl[2][2][16][40]; // P per (rg,pg): [row][32 keys+pad]
    __shared__ __align__(16) float macc[8][16][36];  // 18.4 KiB
    __shared__ float ll[8][16];

    int bid = blockIdx.x;
    int b = bid & 7;                           // XCD-pinned batch
    int i6 = bid >> 3;                         // 0..63
    int qt = (i6 < 32) ? (63 - i6) : (i6 - 32);// heavy/light pairing (bid, bid+256)
    int len = lengths[b];
    int qbase = qt * 32;
    int t = threadIdx.x;
    int w = t >> 6, lane = t & 63;
    int g = lane >> 4, c = lane & 15;
    int rg = w >> 2, ks = w & 3;
    int pg = ks >> 1, h = ks & 1;

    if (qbase >= len) {                        // fully padded tile -> zeros
        int row = t >> 4, col0 = (t & 15) * 4;
        f32x4 zz = {0.f, 0.f, 0.f, 0.f};
        *(f32x4*)(out + ((size_t)b * SEQ + qbase + row) * DK + col0) = zz;
        return;
    }

    int kend = min(len, qbase + 32);
    int ntiles = (kend + 63) >> 6;

    const short* Qb = Q + ((size_t)b * SEQ + qbase + rg * 16) * DK;
    const short* Kg = K_ + (size_t)b * SEQ * DK;
    const short* Vg = Vt + (size_t)b * DK * SEQ;

    bf16x8 qa0 = *(const bf16x8*)(Qb + c * DK + g * 8);
    bf16x8 qa1 = *(const bf16x8*)(Qb + c * DK + 32 + g * 8);

    int rowcap[4];
    #pragma unroll
    for (int j = 0; j < 4; j++)
        rowcap[j] = min(qbase + rg * 16 + 4 * g + j, len - 1);

    f32x4 z = {0.f, 0.f, 0.f, 0.f};
    f32x4 acc[2] = {z, z};
    float l_r[4] = {0.f, 0.f, 0.f, 0.f};

    // staging map: thread t -> (row 0..63, 16B granule 0..7), XOR-swizzled dest
    int skey = t >> 3, sgr = t & 7;
    const short* kgsrc = Kg + (size_t)skey * DK + sgr * 8;   // + tt*4096
    const short* vgsrc = Vg + (size_t)skey * SEQ + sgr * 8;  // + tt*64  (d = skey)
    int swo = skey * 64 + ((sgr ^ (skey & 7)) << 3);

    // per-wave LDS read bases
    const short* kbase0 = &ksd[0][0][0] + (ks * 16 + c) * 64;
    int ko0 = ((g ^ (c & 7)) << 3);
    int ko1 = (((4 + g) ^ (c & 7)) << 3);
    short* plb = &pl[rg][pg][0][0];
    const short* vbase0 = &vsd[0][0][0] + ((h * 2) * 16 + c) * 64;   // n = 2h, 2h+1
    int vgo = (((pg * 4 + g) ^ (c & 7)) << 3);

    // prologue: stage tile 0, issue tile-1 loads
    bf16x8 kA, vA;
    kA = *(const bf16x8*)kgsrc;
    vA = *(const bf16x8*)vgsrc;
    *(bf16x8*)(&ksd[0][0][0] + swo) = kA;
    *(bf16x8*)(&vsd[0][0][0] + swo) = vA;
    if (ntiles > 1) {
        kA = *(const bf16x8*)(kgsrc + 4096);
        vA = *(const bf16x8*)(vgsrc + 64);
    }
    LDS_BARRIER();

    for (int tt = 0; tt < ntiles; tt++) {
        int cur = tt & 1;
        // issue tile tt+2 loads FIRST (2-deep prefetch, survives raw barriers)
        bf16x8 kB, vB;
        if (tt + 2 < ntiles) {
            kB = *(const bf16x8*)(kgsrc + (size_t)(tt + 2) * 4096);
            vB = *(const bf16x8*)(vgsrc + (tt + 2) * 64);
        }
        // QK^T: 16 rows x 16 keys, k=64 via 2 MFMA
        bf16x8 kf0 = *(const bf16x8*)(kbase0 + cur * 4096 + ko0);
        bf16x8 kf1 = *(const bf16x8*)(kbase0 + cur * 4096 + ko1);
        f32x4 sf = __builtin_amdgcn_mfma_f32_16x16x32_bf16(qa0, kf0, z, 0, 0, 0);
        sf = __builtin_amdgcn_mfma_f32_16x16x32_bf16(qa1, kf1, sf, 0, 0, 0);
        // mask + exp2 + l accumulation + P write (4 values/lane)
        int key = tt * 64 + ks * 16 + c;
        #pragma unroll
        for (int j = 0; j < 4; j++) {
            float s = (key > rowcap[j]) ? -1e30f : sf[j];
            float p = exp2f(s - FIXMAX2);
            l_r[j] += p;
            plb[(4 * g + j) * 40 + h * 16 + c] = f2bf(p);
        }
        LDS_BARRIER();   // P visible to pair partner
        // PV: 32 keys (pair), 2 d-frags
        bf16x8 pa = *(const bf16x8*)(plb + c * 40 + g * 8);
        bf16x8 vf0 = *(const bf16x8*)(vbase0 + cur * 4096 + vgo);
        bf16x8 vf1 = *(const bf16x8*)(vbase0 + cur * 4096 + 1024 + vgo);
        acc[0] = __builtin_amdgcn_mfma_f32_16x16x32_bf16(pa, vf0, acc[0], 0, 0, 0);
        acc[1] = __builtin_amdgcn_mfma_f32_16x16x32_bf16(pa, vf1, acc[1], 0, 0, 0);
        // stage tile tt+1 into the other buffer (counted vmcnt lands here)
        if (tt + 1 < ntiles) {
            *(bf16x8*)(&ksd[cur ^ 1][0][0] + swo) = kA;
            *(bf16x8*)(&vsd[cur ^ 1][0][0] + swo) = vA;
        }
        kA = kB; vA = vB;
        LDS_BARRIER();
    }

    // l reduction across the 16 c-lanes of each row
    #pragma unroll
    for (int d = 1; d < 16; d <<= 1)
        #pragma unroll
        for (int j = 0; j < 4; j++) l_r[j] += __shfl_xor(l_r[j], d);

    #pragma unroll
    for (int nl = 0; nl < 2; nl++)
        #pragma unroll
        for (int j = 0; j < 4; j++)
            macc[w][4 * g + j][nl * 16 + c] = acc[nl][j];
    if (c == 0) {
        #pragma unroll
        for (int j = 0; j < 4; j++) ll[w][4 * g + j] = l_r[j];
    }
    __syncthreads();
    // merge: O[d] = sum over pair-groups of the matching d-half; L = sum over quarters
    {
        int row = t >> 4, dseg = t & 15;
        int rgo = row >> 4, r16 = row & 15;
        int r = qbase + row;
        float o[4] = {0.f, 0.f, 0.f, 0.f};
        if (r < len) {
            float L = ll[rgo * 4 + 0][r16] + ll[rgo * 4 + 1][r16]
                    + ll[rgo * 4 + 2][r16] + ll[rgo * 4 + 3][r16];
            int n = dseg >> 2;              // d-frag 0..3
            int h2 = n >> 1, nl = n & 1;
            int col = nl * 16 + (dseg & 3) * 4;
            float inv = 1.f / L;
            #pragma unroll
            for (int i = 0; i < 4; i++)
                o[i] = (macc[rgo * 4 + h2][r16][col + i]
                      + macc[rgo * 4 + 2 + h2][r16][col + i]) * inv;
        }
        *(f32x4*)(out + ((size_t)b * SEQ + r) * DK + dseg * 4) =
            *(f32x4*)o;
    }
}

extern "C" void kernel_launch(void* const* d_in, const int* in_sizes, int n_in,
                              void* d_out, int out_size, void* d_ws, size_t ws_size,
                              hipStream_t stream) {
    const float* x  = (const float*)d_in[0];
    const unsigned* mask = (const unsigned*)d_in[1];
    const float* Wq = (const float*)d_in[2];
    const float* bq = (const float*)d_in[3];
    const float* Wk = (const float*)d_in[4];
    const float* bk = (const float*)d_in[5];
    const float* Wv = (const float*)d_in[6];
    const float* bv = (const float*)d_in[7];
    float* out = (float*)d_out;

    char* ws = (char*)d_ws;
    int*   lengths = (int*)ws;                          // 256 B
    short* Wp = (short*)(ws + 256);                     // 384 KiB (Wp2 layout)
    short* Q  = (short*)(ws + 393472);                  // 2 MiB
    short* K  = (short*)(ws + 2490624);                 // 2 MiB
    short* Vt = (short*)(ws + 4587776);                 // 2 MiB

    hipLaunchKernelGGL(prep_kernel, dim3(776), dim3(256), 0, stream, mask, Wq, Wk, Wv, lengths, Wp);
    hipLaunchKernelGGL(qkv_kernel, dim3(512), dim3(256), 0, stream,
                       x, bq, bk, bv, Wp, Q, K, Vt);
    hipLaunchKernelGGL(attn_kernel, dim3(NB * 64), dim3(512), 0, stream,
                       Q, K, Vt, lengths, out);
}

// Round 14
// 55.209 us; speedup vs baseline: 1.1153x; 1.1153x over previous
//
#include <hip/hip_runtime.h>
#include <hip/hip_bf16.h>

#define NB 8
#define SEQ 2048
#define HD 1024
#define DK 64

// exp2-domain constants: Q pre-scaled by 0.125/ln2, fixed softmax base 8/ln2
#define QSCALE 0.1803368801111244f
#define FIXMAX2 11.541560327111708f

typedef __attribute__((ext_vector_type(4))) float f32x4;
typedef __attribute__((ext_vector_type(8))) short bf16x8;
typedef __attribute__((ext_vector_type(4))) unsigned short u16x4;

// raw barrier: LDS-only fence (lgkmcnt), NO vmcnt drain -> global loads stay in flight
#define LDS_BARRIER() asm volatile("s_waitcnt lgkmcnt(0)\n\ts_barrier" ::: "memory")

__device__ __forceinline__ short f2bf(float f) {
    union { float f; unsigned u; } v; v.f = f;
    unsigned r = v.u + 0x7fffu + ((v.u >> 16) & 1u);
    return (short)(r >> 16);
}
__device__ __forceinline__ bf16x8 pack8(f32x4 v0, f32x4 v1) {
    union { bf16x8 v; __hip_bfloat162 h[4]; } u;
    u.h[0] = __float22bfloat162_rn(make_float2(v0[0], v0[1]));
    u.h[1] = __float22bfloat162_rn(make_float2(v0[2], v0[3]));
    u.h[2] = __float22bfloat162_rn(make_float2(v1[0], v1[1]));
    u.h[3] = __float22bfloat162_rn(make_float2(v1[2], v1[3]));
    return u.v;
}

// ---------------- prep: W pack (blocks 0..767) + lengths (768..775) ----------------
// Wp2[(((kbg*4+cg)*2+kh)*3+fr)*512 + lane*8 + j] = W_m[k][colm]
__global__ void prep_kernel(const unsigned* __restrict__ mask,
                            const float* __restrict__ Wq, const float* __restrict__ Wk,
                            const float* __restrict__ Wv,
                            int* __restrict__ lengths, short* __restrict__ Wp) {
    if (blockIdx.x < 768) {
        int idx = blockIdx.x * 256 + threadIdx.x;     // 0..196607
        int j = idx & 7, lane = (idx >> 3) & 63;
        int slot = idx >> 9;                          // 0..383
        int fr = slot % 3, q2 = slot / 3;
        int kh = q2 & 1, cg = (q2 >> 1) & 3, kbg = q2 >> 3;
        int g = lane >> 4, c = lane & 15;
        int n = cg * 3 + fr;
        int m = n >> 2, colm = (n & 3) * 16 + c;
        int k = kbg * 64 + kh * 32 + g * 8 + j;
        const float* W = (m == 0) ? Wq : (m == 1) ? Wk : Wv;
        Wp[idx] = f2bf(W[(size_t)k * DK + colm]);
        return;
    }
    __shared__ int sdet;
    __shared__ int scnt;
    int b = blockIdx.x - 768, t = threadIdx.x;
    if (t == 0) { sdet = 0; scnt = 0; }
    __syncthreads();
    int det = 0;
    for (int i = t; i < 4096; i += 256) {
        unsigned w = mask[i];
        if (w > 1u && w != 0x3F800000u) det = 1;
    }
    if (det) atomicOr(&sdet, 1);
    __syncthreads();
    int cnt = 0;
    if (sdet) {
        const unsigned char* m8 = (const unsigned char*)mask;
        for (int s = t; s < SEQ; s += 256) cnt += (m8[b * SEQ + s] == 0) ? 1 : 0;
    } else {
        for (int s = t; s < SEQ; s += 256) cnt += (mask[b * SEQ + s] == 0u) ? 1 : 0;
    }
    atomicAdd(&scnt, cnt);
    __syncthreads();
    if (t == 0) lengths[b] = scnt;
}

// ---------------- QKV v11: bf16-in-LDS dbuf GEMM, counted-vmcnt pipeline -----------
__global__ __launch_bounds__(256) void qkv_kernel(
    const float* __restrict__ x,
    const float* __restrict__ bq, const float* __restrict__ bk, const float* __restrict__ bv,
    const short* __restrict__ Wp,
    short* __restrict__ Q, short* __restrict__ K, short* __restrict__ Vt) {
    __shared__ short xs[2][32][64];    // 8 KiB bf16, granule-swizzled
    int t = threadIdx.x;
    int cg = t >> 6, lane = t & 63;
    int g = lane >> 4, c = lane & 15;
    int r0 = blockIdx.x * 32;
    int bb = r0 >> 11, sbase = r0 & (SEQ - 1);

    int srow = t >> 3, ch = t & 7;
    const float* xsrc = x + (size_t)(r0 + srow) * HD + ch * 8;
    short* wbase = &xs[0][0][0];
    int wo = srow * 64 + ((ch ^ (srow & 7)) << 3);    // shorts

    const short* wpw = Wp + (size_t)cg * 3072 + (size_t)lane * 8;

    f32x4 z = {0.f, 0.f, 0.f, 0.f};
    f32x4 acc[2][3];
    #pragma unroll
    for (int rf = 0; rf < 2; rf++)
        #pragma unroll
        for (int fr = 0; fr < 3; fr++) acc[rf][fr] = z;

    // prologue: stage step 0 (convert at write), preload B step 0, issue x step 1
    {
        f32x4 x0 = *(const f32x4*)xsrc;
        f32x4 x1 = *(const f32x4*)(xsrc + 4);
        *(bf16x8*)(wbase + wo) = pack8(x0, x1);
    }
    bf16x8 Bc[2][3];
    #pragma unroll
    for (int kh = 0; kh < 2; kh++)
        #pragma unroll
        for (int fr = 0; fr < 3; fr++)
            Bc[kh][fr] = *(const bf16x8*)(wpw + kh * 1536 + fr * 512);
    f32x4 nxA0 = *(const f32x4*)(xsrc + 64);
    f32x4 nxA1 = *(const f32x4*)(xsrc + 68);
    LDS_BARRIER();

    const short* rbase0 = &xs[0][0][0] + c * 64;   // + cur*2048 + rf*1024 + chunk*8
    #pragma unroll
    for (int kbg = 0; kbg < 16; kbg++) {
        int cur = kbg & 1;
        // issue x loads for kbg+2 (2-deep) and B loads for kbg+1 (1-deep) FIRST
        f32x4 nxB0, nxB1;
        bf16x8 Bn[2][3];
        if (kbg < 14) {
            const float* p = xsrc + (kbg + 2) * 64;
            nxB0 = *(const f32x4*)p;
            nxB1 = *(const f32x4*)(p + 4);
        }
        if (kbg < 15) {
            #pragma unroll
            for (int kh = 0; kh < 2; kh++)
                #pragma unroll
                for (int fr = 0; fr < 3; fr++)
                    Bn[kh][fr] = *(const bf16x8*)(wpw + (kbg + 1) * 12288 + kh * 1536 + fr * 512);
        }
        // A frags: direct bf16 ds_read_b128 (no conversion)
        bf16x8 Af[2][2];
        #pragma unroll
        for (int rf = 0; rf < 2; rf++)
            #pragma unroll
            for (int kh = 0; kh < 2; kh++)
                Af[rf][kh] = *(const bf16x8*)(rbase0 + cur * 2048 + rf * 1024
                                              + (((kh * 4 + g) ^ (c & 7)) << 3));
        #pragma unroll
        for (int kh = 0; kh < 2; kh++)
            #pragma unroll
            for (int fr = 0; fr < 3; fr++)
                #pragma unroll
                for (int rf = 0; rf < 2; rf++)
                    acc[rf][fr] = __builtin_amdgcn_mfma_f32_16x16x32_bf16(Af[rf][kh], Bc[kh][fr], acc[rf][fr], 0, 0, 0);
        if (kbg < 15) {
            // counted vmcnt wait lands here (nxA issued 2 steps ago)
            *(bf16x8*)(wbase + (cur ^ 1) * 2048 + wo) = pack8(nxA0, nxA1);
            #pragma unroll
            for (int kh = 0; kh < 2; kh++)
                #pragma unroll
                for (int fr = 0; fr < 3; fr++) Bc[kh][fr] = Bn[kh][fr];
        }
        if (kbg < 14) { nxA0 = nxB0; nxA1 = nxB1; }
        LDS_BARRIER();
    }

    // epilogue
    #pragma unroll
    for (int rf = 0; rf < 2; rf++)
        #pragma unroll
        for (int fr = 0; fr < 3; fr++) {
            int n = cg * 3 + fr;
            int m = n >> 2, colm = (n & 3) * 16 + c;
            const float* bias = (m == 0) ? bq : (m == 1) ? bk : bv;
            float bv_ = bias[colm];
            if (m == 2) {
                u16x4 pk;
                #pragma unroll
                for (int j = 0; j < 4; j++) pk[j] = (unsigned short)f2bf(acc[rf][fr][j] + bv_);
                int srw = sbase + rf * 16 + 4 * g;
                *(u16x4*)(Vt + (size_t)bb * DK * SEQ + (size_t)colm * SEQ + srw) = pk;
            } else {
                #pragma unroll
                for (int j = 0; j < 4; j++) {
                    int row = r0 + rf * 16 + 4 * g + j;
                    float s = acc[rf][fr][j] + bv_;
                    if (m == 0) Q[(size_t)row * DK + colm] = f2bf(s * QSCALE);
                    else        K[(size_t)row * DK + colm] = f2bf(s);
                }
            }
        }
}

// ---------------- flash attention v14: v12 structure + register diet ---------------
// Block = one 32-row q-tile, 8 waves on interleaved 64-key stripes (tt += 8).
// Register diet vs v12: no cross-tile K prefetch, V loaded per-d-frag inside PV.
// Target <128 VGPR -> 4 waves/SIMD (16 waves/CU).
__global__ __launch_bounds__(512) void attn_kernel(
    const short* __restrict__ Q, const short* __restrict__ K_, const short* __restrict__ Vt,
    const int* __restrict__ lengths, float* __restrict__ out) {
    __shared__ float macc[8][32][66];          // merge buffer (67.6 KiB)
    __shared__ float ll[8][32];
    short* plds = (short*)&macc[0][0][0];      // aliased P-transpose region (35.8 KiB)

    int bid = blockIdx.x;
    int b = bid & 7;                           // XCD-pinned batch
    int qt = 63 - (bid >> 3);                  // heavy tiles dispatch first
    int len = lengths[b];
    int qbase = qt * 32;
    int t = threadIdx.x;
    int w = t >> 6, lane = t & 63;
    int g = lane >> 4, c = lane & 15;

    if (qbase >= len) {                        // fully padded tile -> zeros
        int row = t >> 4, col0 = (t & 15) * 4;
        f32x4 zz = {0.f, 0.f, 0.f, 0.f};
        *(f32x4*)(out + ((size_t)b * SEQ + qbase + row) * DK + col0) = zz;
        return;
    }

    int kend = min(len, qbase + 32);
    int ntiles = (kend + 63) >> 6;
    const short* Qb = Q + ((size_t)b * SEQ + qbase) * DK;
    const short* Kb = K_ + (size_t)b * SEQ * DK;
    const short* Vb = Vt + (size_t)b * DK * SEQ;

    bf16x8 qa[2][2];
    #pragma unroll
    for (int f = 0; f < 2; f++)
        #pragma unroll
        for (int kh = 0; kh < 2; kh++)
            qa[f][kh] = *(const bf16x8*)(Qb + (f * 16 + c) * DK + kh * 32 + g * 8);

    int rowcap[2][4];
    #pragma unroll
    for (int f = 0; f < 2; f++)
        #pragma unroll
        for (int j = 0; j < 4; j++)
            rowcap[f][j] = min(qbase + f * 16 + 4 * g + j, len - 1);

    f32x4 z = {0.f, 0.f, 0.f, 0.f};
    f32x4 acc[2][4];
    float l_r[2][4];
    #pragma unroll
    for (int f = 0; f < 2; f++) {
        #pragma unroll
        for (int n = 0; n < 4; n++) acc[f][n] = z;
        #pragma unroll
        for (int j = 0; j < 4; j++) l_r[f][j] = 0.f;
    }

    short* pldsw = plds + w * 2240;            // [2][16][70] shorts per wave

    for (int tt = w; tt < ntiles; tt += 8) {
        int kb = tt * 64;
        // half-0 K loads, then half-1 loads issued BEFORE half-0 MFMAs (MLP)
        bf16x8 kh0[2][2], kh1[2][2];
        #pragma unroll
        for (int kt = 0; kt < 2; kt++) {
            const short* kp = Kb + (size_t)(kb + kt * 16 + c) * DK + g * 8;
            kh0[kt][0] = *(const bf16x8*)kp;
            kh0[kt][1] = *(const bf16x8*)(kp + 32);
        }
        #pragma unroll
        for (int kt = 0; kt < 2; kt++) {
            const short* kp = Kb + (size_t)(kb + 32 + kt * 16 + c) * DK + g * 8;
            kh1[kt][0] = *(const bf16x8*)kp;
            kh1[kt][1] = *(const bf16x8*)(kp + 32);
        }
        f32x4 sf[2][4];
        #pragma unroll
        for (int kt = 0; kt < 2; kt++)
            #pragma unroll
            for (int f = 0; f < 2; f++) {
                f32x4 t0 = __builtin_amdgcn_mfma_f32_16x16x32_bf16(qa[f][0], kh0[kt][0], z, 0, 0, 0);
                sf[f][kt] = __builtin_amdgcn_mfma_f32_16x16x32_bf16(qa[f][1], kh0[kt][1], t0, 0, 0, 0);
            }
        #pragma unroll
        for (int kt = 0; kt < 2; kt++)
            #pragma unroll
            for (int f = 0; f < 2; f++) {
                f32x4 t0 = __builtin_amdgcn_mfma_f32_16x16x32_bf16(qa[f][0], kh1[kt][0], z, 0, 0, 0);
                sf[f][kt + 2] = __builtin_amdgcn_mfma_f32_16x16x32_bf16(qa[f][1], kh1[kt][1], t0, 0, 0, 0);
            }
        // mask + exp2 + per-lane l accumulation (no cross-lane ops)
        #pragma unroll
        for (int kt = 0; kt < 4; kt++) {
            int key = kb + kt * 16 + c;
            #pragma unroll
            for (int f = 0; f < 2; f++)
                #pragma unroll
                for (int j = 0; j < 4; j++) {
                    float s = (key > rowcap[f][j]) ? -1e30f : sf[f][kt][j];
                    float p = exp2f(s - FIXMAX2);
                    sf[f][kt][j] = p;
                    l_r[f][j] += p;
                }
        }
        // P: D-layout -> LDS -> A-layout (wave-private lockstep, no barrier)
        #pragma unroll
        for (int f = 0; f < 2; f++)
            #pragma unroll
            for (int kt = 0; kt < 4; kt++)
                #pragma unroll
                for (int j = 0; j < 4; j++)
                    pldsw[f * 1120 + (4 * g + j) * 70 + kt * 16 + c] = f2bf(sf[f][kt][j]);
        bf16x8 pa[2][2];
        #pragma unroll
        for (int f = 0; f < 2; f++) {
            pa[f][0] = *(const bf16x8*)(pldsw + f * 1120 + c * 70 + g * 8);
            pa[f][1] = *(const bf16x8*)(pldsw + f * 1120 + c * 70 + 32 + g * 8);
        }
        // PV: V loaded per-d-frag inside the loop (8 transient regs, not 32 live)
        #pragma unroll
        for (int n = 0; n < 4; n++) {
            const short* vp = Vb + (size_t)(n * 16 + c) * SEQ + kb + g * 8;
            bf16x8 v0 = *(const bf16x8*)vp;
            bf16x8 v1 = *(const bf16x8*)(vp + 32);
            #pragma unroll
            for (int f = 0; f < 2; f++) {
                acc[f][n] = __builtin_amdgcn_mfma_f32_16x16x32_bf16(pa[f][0], v0, acc[f][n], 0, 0, 0);
                acc[f][n] = __builtin_amdgcn_mfma_f32_16x16x32_bf16(pa[f][1], v1, acc[f][n], 0, 0, 0);
            }
        }
    }

    // one-time l reduction across the 16 lanes holding each row
    #pragma unroll
    for (int d = 1; d < 16; d <<= 1)
        #pragma unroll
        for (int f = 0; f < 2; f++)
            #pragma unroll
            for (int j = 0; j < 4; j++) l_r[f][j] += __shfl_xor(l_r[f][j], d);

    __syncthreads();   // plds lifetime over -> reuse as macc
    #pragma unroll
    for (int f = 0; f < 2; f++)
        #pragma unroll
        for (int n = 0; n < 4; n++)
            #pragma unroll
            for (int j = 0; j < 4; j++)
                macc[w][f * 16 + 4 * g + j][n * 16 + c] = acc[f][n][j];
    if (c == 0) {
        #pragma unroll
        for (int f = 0; f < 2; f++)
            #pragma unroll
            for (int j = 0; j < 4; j++)
                ll[w][f * 16 + 4 * g + j] = l_r[f][j];
    }
    __syncthreads();
    // merge: plain sums (all waves share the same fixed max)
    {
        int row = t >> 4, seg = t & 15;
        int r = qbase + row;
        float* op = out + ((size_t)b * SEQ + r) * DK + seg * 4;
        float o[4] = {0.f, 0.f, 0.f, 0.f};
        if (r < len) {
            float L = 0.f;
            #pragma unroll
            for (int wv = 0; wv < 8; wv++) L += ll[wv][row];
            #pragma unroll
            for (int wv = 0; wv < 8; wv++)
                #pragma unroll
                for (int i = 0; i < 4; i++) o[i] += macc[wv][row][seg * 4 + i];
            float inv = 1.f / L;
            #pragma unroll
            for (int i = 0; i < 4; i++) o[i] *= inv;
        }
        #pragma unroll
        for (int i = 0; i < 4; i++) op[i] = o[i];
    }
}

extern "C" void kernel_launch(void* const* d_in, const int* in_sizes, int n_in,
                              void* d_out, int out_size, void* d_ws, size_t ws_size,
                              hipStream_t stream) {
    const float* x  = (const float*)d_in[0];
    const unsigned* mask = (const unsigned*)d_in[1];
    const float* Wq = (const float*)d_in[2];
    const float* bq = (const float*)d_in[3];
    const float* Wk = (const float*)d_in[4];
    const float* bk = (const float*)d_in[5];
    const float* Wv = (const float*)d_in[6];
    const float* bv = (const float*)d_in[7];
    float* out = (float*)d_out;

    char* ws = (char*)d_ws;
    int*   lengths = (int*)ws;                          // 256 B
    short* Wp = (short*)(ws + 256);                     // 384 KiB (Wp2 layout)
    short* Q  = (short*)(ws + 393472);                  // 2 MiB
    short* K  = (short*)(ws + 2490624);                 // 2 MiB
    short* Vt = (short*)(ws + 4587776);                 // 2 MiB

    hipLaunchKernelGGL(prep_kernel, dim3(776), dim3(256), 0, stream, mask, Wq, Wk, Wv, lengths, Wp);
    hipLaunchKernelGGL(qkv_kernel, dim3(512), dim3(256), 0, stream,
                       x, bq, bk, bv, Wp, Q, K, Vt);
    hipLaunchKernelGGL(attn_kernel, dim3(NB * 64), dim3(512), 0, stream,
                       Q, K, Vt, lengths, out);
}

// Round 15
// 54.786 us; speedup vs baseline: 1.1240x; 1.0077x over previous
//
#include <hip/hip_runtime.h>
#include <hip/hip_bf16.h>

#define NB 8
#define SEQ 2048
#define HD 1024
#define DK 64

// exp2-domain constants: Q pre-scaled by 0.125/ln2, fixed softmax base 8/ln2
#define QSCALE 0.1803368801111244f
#define FIXMAX2 11.541560327111708f

typedef __attribute__((ext_vector_type(4))) float f32x4;
typedef __attribute__((ext_vector_type(8))) short bf16x8;
typedef __attribute__((ext_vector_type(4))) unsigned short u16x4;

// raw barrier: LDS-only fence (lgkmcnt), NO vmcnt drain -> global loads stay in flight
#define LDS_BARRIER() asm volatile("s_waitcnt lgkmcnt(0)\n\ts_barrier" ::: "memory")

__device__ __forceinline__ short f2bf(float f) {
    union { float f; unsigned u; } v; v.f = f;
    unsigned r = v.u + 0x7fffu + ((v.u >> 16) & 1u);
    return (short)(r >> 16);
}
// single v_exp_f32 (exact for x<=0 incl. masked -1e30 -> 0); fallback to libm
__device__ __forceinline__ float fexp2(float x) {
#if __has_builtin(__builtin_amdgcn_exp2f)
    return __builtin_amdgcn_exp2f(x);
#else
    return exp2f(x);
#endif
}
// one-op f32->bf16 (RNE), low 16 bits of v_cvt_pk_bf16_f32
__device__ __forceinline__ short bf16lo(float f) {
    unsigned r;
    asm("v_cvt_pk_bf16_f32 %0, %1, %1" : "=v"(r) : "v"(f));
    return (short)r;
}
__device__ __forceinline__ bf16x8 pack8(f32x4 v0, f32x4 v1) {
    union { bf16x8 v; __hip_bfloat162 h[4]; } u;
    u.h[0] = __float22bfloat162_rn(make_float2(v0[0], v0[1]));
    u.h[1] = __float22bfloat162_rn(make_float2(v0[2], v0[3]));
    u.h[2] = __float22bfloat162_rn(make_float2(v1[0], v1[1]));
    u.h[3] = __float22bfloat162_rn(make_float2(v1[2], v1[3]));
    return u.v;
}

// ---------------- prep: W pack (blocks 0..767) + lengths (768..775) ----------------
// Wp2[(((kbg*4+cg)*2+kh)*3+fr)*512 + lane*8 + j] = W_m[k][colm]
__global__ void prep_kernel(const unsigned* __restrict__ mask,
                            const float* __restrict__ Wq, const float* __restrict__ Wk,
                            const float* __restrict__ Wv,
                            int* __restrict__ lengths, short* __restrict__ Wp) {
    if (blockIdx.x < 768) {
        int idx = blockIdx.x * 256 + threadIdx.x;     // 0..196607
        int j = idx & 7, lane = (idx >> 3) & 63;
        int slot = idx >> 9;                          // 0..383
        int fr = slot % 3, q2 = slot / 3;
        int kh = q2 & 1, cg = (q2 >> 1) & 3, kbg = q2 >> 3;
        int g = lane >> 4, c = lane & 15;
        int n = cg * 3 + fr;
        int m = n >> 2, colm = (n & 3) * 16 + c;
        int k = kbg * 64 + kh * 32 + g * 8 + j;
        const float* W = (m == 0) ? Wq : (m == 1) ? Wk : Wv;
        Wp[idx] = f2bf(W[(size_t)k * DK + colm]);
        return;
    }
    __shared__ int sdet;
    __shared__ int scnt;
    int b = blockIdx.x - 768, t = threadIdx.x;
    if (t == 0) { sdet = 0; scnt = 0; }
    __syncthreads();
    int det = 0;
    for (int i = t; i < 4096; i += 256) {
        unsigned w = mask[i];
        if (w > 1u && w != 0x3F800000u) det = 1;
    }
    if (det) atomicOr(&sdet, 1);
    __syncthreads();
    int cnt = 0;
    if (sdet) {
        const unsigned char* m8 = (const unsigned char*)mask;
        for (int s = t; s < SEQ; s += 256) cnt += (m8[b * SEQ + s] == 0) ? 1 : 0;
    } else {
        for (int s = t; s < SEQ; s += 256) cnt += (mask[b * SEQ + s] == 0u) ? 1 : 0;
    }
    atomicAdd(&scnt, cnt);
    __syncthreads();
    if (t == 0) lengths[b] = scnt;
}

// ---------------- QKV v11: bf16-in-LDS dbuf GEMM, counted-vmcnt pipeline -----------
__global__ __launch_bounds__(256) void qkv_kernel(
    const float* __restrict__ x,
    const float* __restrict__ bq, const float* __restrict__ bk, const float* __restrict__ bv,
    const short* __restrict__ Wp,
    short* __restrict__ Q, short* __restrict__ K, short* __restrict__ Vt) {
    __shared__ short xs[2][32][64];    // 8 KiB bf16, granule-swizzled
    int t = threadIdx.x;
    int cg = t >> 6, lane = t & 63;
    int g = lane >> 4, c = lane & 15;
    int r0 = blockIdx.x * 32;
    int bb = r0 >> 11, sbase = r0 & (SEQ - 1);

    int srow = t >> 3, ch = t & 7;
    const float* xsrc = x + (size_t)(r0 + srow) * HD + ch * 8;
    short* wbase = &xs[0][0][0];
    int wo = srow * 64 + ((ch ^ (srow & 7)) << 3);    // shorts

    const short* wpw = Wp + (size_t)cg * 3072 + (size_t)lane * 8;

    f32x4 z = {0.f, 0.f, 0.f, 0.f};
    f32x4 acc[2][3];
    #pragma unroll
    for (int rf = 0; rf < 2; rf++)
        #pragma unroll
        for (int fr = 0; fr < 3; fr++) acc[rf][fr] = z;

    // prologue: stage step 0 (convert at write), preload B step 0, issue x step 1
    {
        f32x4 x0 = *(const f32x4*)xsrc;
        f32x4 x1 = *(const f32x4*)(xsrc + 4);
        *(bf16x8*)(wbase + wo) = pack8(x0, x1);
    }
    bf16x8 Bc[2][3];
    #pragma unroll
    for (int kh = 0; kh < 2; kh++)
        #pragma unroll
        for (int fr = 0; fr < 3; fr++)
            Bc[kh][fr] = *(const bf16x8*)(wpw + kh * 1536 + fr * 512);
    f32x4 nxA0 = *(const f32x4*)(xsrc + 64);
    f32x4 nxA1 = *(const f32x4*)(xsrc + 68);
    LDS_BARRIER();

    const short* rbase0 = &xs[0][0][0] + c * 64;   // + cur*2048 + rf*1024 + chunk*8
    #pragma unroll
    for (int kbg = 0; kbg < 16; kbg++) {
        int cur = kbg & 1;
        // issue x loads for kbg+2 (2-deep) and B loads for kbg+1 (1-deep) FIRST
        f32x4 nxB0, nxB1;
        bf16x8 Bn[2][3];
        if (kbg < 14) {
            const float* p = xsrc + (kbg + 2) * 64;
            nxB0 = *(const f32x4*)p;
            nxB1 = *(const f32x4*)(p + 4);
        }
        if (kbg < 15) {
            #pragma unroll
            for (int kh = 0; kh < 2; kh++)
                #pragma unroll
                for (int fr = 0; fr < 3; fr++)
                    Bn[kh][fr] = *(const bf16x8*)(wpw + (kbg + 1) * 12288 + kh * 1536 + fr * 512);
        }
        // A frags: direct bf16 ds_read_b128 (no conversion)
        bf16x8 Af[2][2];
        #pragma unroll
        for (int rf = 0; rf < 2; rf++)
            #pragma unroll
            for (int kh = 0; kh < 2; kh++)
                Af[rf][kh] = *(const bf16x8*)(rbase0 + cur * 2048 + rf * 1024
                                              + (((kh * 4 + g) ^ (c & 7)) << 3));
        #pragma unroll
        for (int kh = 0; kh < 2; kh++)
            #pragma unroll
            for (int fr = 0; fr < 3; fr++)
                #pragma unroll
                for (int rf = 0; rf < 2; rf++)
                    acc[rf][fr] = __builtin_amdgcn_mfma_f32_16x16x32_bf16(Af[rf][kh], Bc[kh][fr], acc[rf][fr], 0, 0, 0);
        if (kbg < 15) {
            // counted vmcnt wait lands here (nxA issued 2 steps ago)
            *(bf16x8*)(wbase + (cur ^ 1) * 2048 + wo) = pack8(nxA0, nxA1);
            #pragma unroll
            for (int kh = 0; kh < 2; kh++)
                #pragma unroll
                for (int fr = 0; fr < 3; fr++) Bc[kh][fr] = Bn[kh][fr];
        }
        if (kbg < 14) { nxA0 = nxB0; nxA1 = nxB1; }
        LDS_BARRIER();
    }

    // epilogue
    #pragma unroll
    for (int rf = 0; rf < 2; rf++)
        #pragma unroll
        for (int fr = 0; fr < 3; fr++) {
            int n = cg * 3 + fr;
            int m = n >> 2, colm = (n & 3) * 16 + c;
            const float* bias = (m == 0) ? bq : (m == 1) ? bk : bv;
            float bv_ = bias[colm];
            if (m == 2) {
                u16x4 pk;
                #pragma unroll
                for (int j = 0; j < 4; j++) pk[j] = (unsigned short)f2bf(acc[rf][fr][j] + bv_);
                int srw = sbase + rf * 16 + 4 * g;
                *(u16x4*)(Vt + (size_t)bb * DK * SEQ + (size_t)colm * SEQ + srw) = pk;
            } else {
                #pragma unroll
                for (int j = 0; j < 4; j++) {
                    int row = r0 + rf * 16 + 4 * g + j;
                    float s = acc[rf][fr][j] + bv_;
                    if (m == 0) Q[(size_t)row * DK + colm] = f2bf(s * QSCALE);
                    else        K[(size_t)row * DK + colm] = f2bf(s);
                }
            }
        }
}

// ---------------- flash attention v15: v14 + VALU diet (exp2 builtin, cvt_pk, setprio)
__global__ __launch_bounds__(512) void attn_kernel(
    const short* __restrict__ Q, const short* __restrict__ K_, const short* __restrict__ Vt,
    const int* __restrict__ lengths, float* __restrict__ out) {
    __shared__ float macc[8][32][66];          // merge buffer (67.6 KiB)
    __shared__ float ll[8][32];
    short* plds = (short*)&macc[0][0][0];      // aliased P-transpose region (35.8 KiB)

    int bid = blockIdx.x;
    int b = bid & 7;                           // XCD-pinned batch
    int qt = 63 - (bid >> 3);                  // heavy tiles dispatch first
    int len = lengths[b];
    int qbase = qt * 32;
    int t = threadIdx.x;
    int w = t >> 6, lane = t & 63;
    int g = lane >> 4, c = lane & 15;

    if (qbase >= len) {                        // fully padded tile -> zeros
        int row = t >> 4, col0 = (t & 15) * 4;
        f32x4 zz = {0.f, 0.f, 0.f, 0.f};
        *(f32x4*)(out + ((size_t)b * SEQ + qbase + row) * DK + col0) = zz;
        return;
    }

    int kend = min(len, qbase + 32);
    int ntiles = (kend + 63) >> 6;
    const short* Qb = Q + ((size_t)b * SEQ + qbase) * DK;
    const short* Kb = K_ + (size_t)b * SEQ * DK;
    const short* Vb = Vt + (size_t)b * DK * SEQ;

    bf16x8 qa[2][2];
    #pragma unroll
    for (int f = 0; f < 2; f++)
        #pragma unroll
        for (int kh = 0; kh < 2; kh++)
            qa[f][kh] = *(const bf16x8*)(Qb + (f * 16 + c) * DK + kh * 32 + g * 8);

    int rowcap[2][4];
    #pragma unroll
    for (int f = 0; f < 2; f++)
        #pragma unroll
        for (int j = 0; j < 4; j++)
            rowcap[f][j] = min(qbase + f * 16 + 4 * g + j, len - 1);

    f32x4 z = {0.f, 0.f, 0.f, 0.f};
    f32x4 acc[2][4];
    float l_r[2][4];
    #pragma unroll
    for (int f = 0; f < 2; f++) {
        #pragma unroll
        for (int n = 0; n < 4; n++) acc[f][n] = z;
        #pragma unroll
        for (int j = 0; j < 4; j++) l_r[f][j] = 0.f;
    }

    short* pldsw = plds + w * 2240;            // [2][16][70] shorts per wave

    for (int tt = w; tt < ntiles; tt += 8) {
        int kb = tt * 64;
        // half-0 K loads, then half-1 loads issued BEFORE half-0 MFMAs (MLP)
        bf16x8 kh0[2][2], kh1[2][2];
        #pragma unroll
        for (int kt = 0; kt < 2; kt++) {
            const short* kp = Kb + (size_t)(kb + kt * 16 + c) * DK + g * 8;
            kh0[kt][0] = *(const bf16x8*)kp;
            kh0[kt][1] = *(const bf16x8*)(kp + 32);
        }
        #pragma unroll
        for (int kt = 0; kt < 2; kt++) {
            const short* kp = Kb + (size_t)(kb + 32 + kt * 16 + c) * DK + g * 8;
            kh1[kt][0] = *(const bf16x8*)kp;
            kh1[kt][1] = *(const bf16x8*)(kp + 32);
        }
        f32x4 sf[2][4];
        __builtin_amdgcn_s_setprio(1);
        #pragma unroll
        for (int kt = 0; kt < 2; kt++)
            #pragma unroll
            for (int f = 0; f < 2; f++) {
                f32x4 t0 = __builtin_amdgcn_mfma_f32_16x16x32_bf16(qa[f][0], kh0[kt][0], z, 0, 0, 0);
                sf[f][kt] = __builtin_amdgcn_mfma_f32_16x16x32_bf16(qa[f][1], kh0[kt][1], t0, 0, 0, 0);
            }
        #pragma unroll
        for (int kt = 0; kt < 2; kt++)
            #pragma unroll
            for (int f = 0; f < 2; f++) {
                f32x4 t0 = __builtin_amdgcn_mfma_f32_16x16x32_bf16(qa[f][0], kh1[kt][0], z, 0, 0, 0);
                sf[f][kt + 2] = __builtin_amdgcn_mfma_f32_16x16x32_bf16(qa[f][1], kh1[kt][1], t0, 0, 0, 0);
            }
        __builtin_amdgcn_s_setprio(0);
        // mask + exp2 (single v_exp_f32) + per-lane l accumulation
        #pragma unroll
        for (int kt = 0; kt < 4; kt++) {
            int key = kb + kt * 16 + c;
            #pragma unroll
            for (int f = 0; f < 2; f++)
                #pragma unroll
                for (int j = 0; j < 4; j++) {
                    float s = (key > rowcap[f][j]) ? -1e30f : sf[f][kt][j];
                    float p = fexp2(s - FIXMAX2);
                    sf[f][kt][j] = p;
                    l_r[f][j] += p;
                }
        }
        // P: D-layout -> LDS -> A-layout (wave-private lockstep, no barrier)
        // single-op v_cvt_pk_bf16_f32 per value (was 4-op scalar f2bf)
        #pragma unroll
        for (int f = 0; f < 2; f++)
            #pragma unroll
            for (int kt = 0; kt < 4; kt++)
                #pragma unroll
                for (int j = 0; j < 4; j++)
                    pldsw[f * 1120 + (4 * g + j) * 70 + kt * 16 + c] = bf16lo(sf[f][kt][j]);
        bf16x8 pa[2][2];
        #pragma unroll
        for (int f = 0; f < 2; f++) {
            pa[f][0] = *(const bf16x8*)(pldsw + f * 1120 + c * 70 + g * 8);
            pa[f][1] = *(const bf16x8*)(pldsw + f * 1120 + c * 70 + 32 + g * 8);
        }
        // PV: V loaded per-d-frag inside the loop (8 transient regs, not 32 live)
        #pragma unroll
        for (int n = 0; n < 4; n++) {
            const short* vp = Vb + (size_t)(n * 16 + c) * SEQ + kb + g * 8;
            bf16x8 v0 = *(const bf16x8*)vp;
            bf16x8 v1 = *(const bf16x8*)(vp + 32);
            __builtin_amdgcn_s_setprio(1);
            #pragma unroll
            for (int f = 0; f < 2; f++) {
                acc[f][n] = __builtin_amdgcn_mfma_f32_16x16x32_bf16(pa[f][0], v0, acc[f][n], 0, 0, 0);
                acc[f][n] = __builtin_amdgcn_mfma_f32_16x16x32_bf16(pa[f][1], v1, acc[f][n], 0, 0, 0);
            }
            __builtin_amdgcn_s_setprio(0);
        }
    }

    // one-time l reduction across the 16 lanes holding each row
    #pragma unroll
    for (int d = 1; d < 16; d <<= 1)
        #pragma unroll
        for (int f = 0; f < 2; f++)
            #pragma unroll
            for (int j = 0; j < 4; j++) l_r[f][j] += __shfl_xor(l_r[f][j], d);

    __syncthreads();   // plds lifetime over -> reuse as macc
    #pragma unroll
    for (int f = 0; f < 2; f++)
        #pragma unroll
        for (int n = 0; n < 4; n++)
            #pragma unroll
            for (int j = 0; j < 4; j++)
                macc[w][f * 16 + 4 * g + j][n * 16 + c] = acc[f][n][j];
    if (c == 0) {
        #pragma unroll
        for (int f = 0; f < 2; f++)
            #pragma unroll
            for (int j = 0; j < 4; j++)
                ll[w][f * 16 + 4 * g + j] = l_r[f][j];
    }
    __syncthreads();
    // merge: plain sums (all waves share the same fixed max)
    {
        int row = t >> 4, seg = t & 15;
        int r = qbase + row;
        float* op = out + ((size_t)b * SEQ + r) * DK + seg * 4;
        float o[4] = {0.f, 0.f, 0.f, 0.f};
        if (r < len) {
            float L = 0.f;
            #pragma unroll
            for (int wv = 0; wv < 8; wv++) L += ll[wv][row];
            #pragma unroll
            for (int wv = 0; wv < 8; wv++)
                #pragma unroll
                for (int i = 0; i < 4; i++) o[i] += macc[wv][row][seg * 4 + i];
            float inv = 1.f / L;
            #pragma unroll
            for (int i = 0; i < 4; i++) o[i] *= inv;
        }
        #pragma unroll
        for (int i = 0; i < 4; i++) op[i] = o[i];
    }
}

extern "C" void kernel_launch(void* const* d_in, const int* in_sizes, int n_in,
                              void* d_out, int out_size, void* d_ws, size_t ws_size,
                              hipStream_t stream) {
    const float* x  = (const float*)d_in[0];
    const unsigned* mask = (const unsigned*)d_in[1];
    const float* Wq = (const float*)d_in[2];
    const float* bq = (const float*)d_in[3];
    const float* Wk = (const float*)d_in[4];
    const float* bk = (const float*)d_in[5];
    const float* Wv = (const float*)d_in[6];
    const float* bv = (const float*)d_in[7];
    float* out = (float*)d_out;

    char* ws = (char*)d_ws;
    int*   lengths = (int*)ws;                          // 256 B
    short* Wp = (short*)(ws + 256);                     // 384 KiB (Wp2 layout)
    short* Q  = (short*)(ws + 393472);                  // 2 MiB
    short* K  = (short*)(ws + 2490624);                 // 2 MiB
    short* Vt = (short*)(ws + 4587776);                 // 2 MiB

    hipLaunchKernelGGL(prep_kernel, dim3(776), dim3(256), 0, stream, mask, Wq, Wk, Wv, lengths, Wp);
    hipLaunchKernelGGL(qkv_kernel, dim3(512), dim3(256), 0, stream,
                       x, bq, bk, bv, Wp, Q, K, Vt);
    hipLaunchKernelGGL(attn_kernel, dim3(NB * 64), dim3(512), 0, stream,
                       Q, K, Vt, lengths, out);
}